// Round 1
// 245.060 us; speedup vs baseline: 1.0773x; 1.0773x over previous
//
#include <hip/hip_runtime.h>
#include <hip/hip_bf16.h>

#define NN 50000
#define EE 800000
#define FF 144
#define NBLK 196   // ceil(NN/256)

typedef __hip_bfloat16 bf16;
typedef __attribute__((ext_vector_type(8))) short short8;
typedef __attribute__((ext_vector_type(4))) float floatx4;
typedef __attribute__((ext_vector_type(2))) float float2v;

__device__ inline float blo(unsigned x) { return __uint_as_float(x << 16); }
__device__ inline float bhi(unsigned x) { return __uint_as_float(x & 0xffff0000u); }

// ---- fp8 e4m3 pack/unpack (gfx950 OCP) ----
__device__ inline void dec4fma(float* a, float l, unsigned d) {
    float2v p0 = __builtin_amdgcn_cvt_pk_f32_fp8((int)d, false);
    float2v p1 = __builtin_amdgcn_cvt_pk_f32_fp8((int)d, true);
    a[0] = fmaf(l, p0.x, a[0]);
    a[1] = fmaf(l, p0.y, a[1]);
    a[2] = fmaf(l, p1.x, a[2]);
    a[3] = fmaf(l, p1.y, a[3]);
}
__device__ inline void fma16q(float* a, float l, uint4 u) {
    dec4fma(a + 0, l, u.x);
    dec4fma(a + 4, l, u.y);
    dec4fma(a + 8, l, u.z);
    dec4fma(a + 12, l, u.w);
}
__device__ inline unsigned enc4(float a, float b, float c, float d) {
    int w = __builtin_amdgcn_cvt_pk_fp8_f32(a, b, 0, false);
    w = __builtin_amdgcn_cvt_pk_fp8_f32(c, d, w, true);
    return (unsigned)w;
}

// ---------------- edge_index int64-layout detection ----------------

__global__ void detect_k(const int* __restrict__ ei, int* __restrict__ flag) {
    __shared__ int nz;
    if (threadIdx.x == 0) nz = 0;
    __syncthreads();
    if (ei[2 * threadIdx.x + 1] != 0) atomicAdd(&nz, 1);
    __syncthreads();
    if (threadIdx.x == 0) *flag = (nz == 0) ? 1 : 0;
}

__device__ inline void load_edge(const int* ei, int e, int flag, int& r, int& c) {
    if (flag) { r = ei[2 * e]; c = ei[2 * EE + 2 * e]; }
    else      { r = ei[e];     c = ei[EE + e]; }
}

// ---------------- x fp32 -> bf16 + fp8, 16 elements/thread ----------------

__global__ void cvt_k(const float* __restrict__ x, bf16* __restrict__ xb,
                      unsigned char* __restrict__ xq) {
    int t = blockIdx.x * 256 + threadIdx.x;
    if (t >= NN * FF / 16) return;
    const float4* xp = (const float4*)x + t * 4;
    float4 v0 = xp[0], v1 = xp[1], v2 = xp[2], v3 = xp[3];
    float f[16] = {v0.x, v0.y, v0.z, v0.w, v1.x, v1.y, v1.z, v1.w,
                   v2.x, v2.y, v2.z, v2.w, v3.x, v3.y, v3.z, v3.w};
    unsigned short hs[16];
    #pragma unroll
    for (int j = 0; j < 16; ++j) {
        bf16 b = (bf16)f[j];
        hs[j] = *(unsigned short*)&b;
    }
    uint4* xbq = (uint4*)xb + t * 2;
    xbq[0] = ((uint4*)hs)[0];
    xbq[1] = ((uint4*)hs)[1];
    uint4 q;
    q.x = enc4(f[0], f[1], f[2], f[3]);
    q.y = enc4(f[4], f[5], f[6], f[7]);
    q.z = enc4(f[8], f[9], f[10], f[11]);
    q.w = enc4(f[12], f[13], f[14], f[15]);
    ((uint4*)xq)[t] = q;
}

// ---------------- W fp32 (K,i,o) -> bf16 transposed padded image wtb[ph][o][i] ----------------

__global__ void cvtw_k(const float* __restrict__ wt, short* __restrict__ wtb) {
    int t = blockIdx.x * 256 + threadIdx.x;
    if (t >= 3 * FF * 168) return;
    int ph = t / (FF * 168);
    int rem = t - ph * FF * 168;
    int o = rem / 168;
    int i = rem - o * 168;
    short v = 0;
    if (i < FF) {
        bf16 b = (bf16)wt[ph * FF * FF + i * FF + o];
        v = *(const short*)&b;
    }
    wtb[t] = v;
}

// ---------------- graph preprocessing ----------------

__global__ void hist_k(const int* __restrict__ ei, int* __restrict__ cnt,
                       const int* __restrict__ flagp) {
    int flag = *flagp;
    int e = blockIdx.x * 256 + threadIdx.x;
    if (e >= EE) return;
    int r, c; load_edge(ei, e, flag, r, c);
    if (r != c) atomicAdd(&cnt[r], 1);
}

// ---------------- multi-block exclusive scan (dinv fused into phase 1) ----------------

__global__ void scan1_k(const int* __restrict__ cnt, int* __restrict__ rowptr,
                        int* __restrict__ bsum, float* __restrict__ dinv) {
    __shared__ int wsum[4], woff[4];
    int b = blockIdx.x, tid = threadIdx.x;
    int wv = tid >> 6, ln = tid & 63;
    int i = b * 256 + tid;
    int v = (i < NN) ? cnt[i] : 0;
    if (i < NN) dinv[i] = v > 0 ? rsqrtf((float)v) : 0.f;
    int x = v;
    #pragma unroll
    for (int off = 1; off < 64; off <<= 1) {
        int t = __shfl_up(x, off, 64);
        if (ln >= off) x += t;
    }
    if (ln == 63) wsum[wv] = x;
    __syncthreads();
    if (tid == 0) {
        int s = 0;
        #pragma unroll
        for (int j = 0; j < 4; ++j) { woff[j] = s; s += wsum[j]; }
        bsum[b] = s;
    }
    __syncthreads();
    if (i < NN) rowptr[i] = woff[wv] + (x - v);
}

__global__ void scan2_k(int* __restrict__ bsum, int* __restrict__ rowptr) {
    __shared__ int wsum[4], woff[4];
    int tid = threadIdx.x;
    int wv = tid >> 6, ln = tid & 63;
    int v = (tid < NBLK) ? bsum[tid] : 0;
    int x = v;
    #pragma unroll
    for (int off = 1; off < 64; off <<= 1) {
        int t = __shfl_up(x, off, 64);
        if (ln >= off) x += t;
    }
    if (ln == 63) wsum[wv] = x;
    __syncthreads();
    if (tid == 0) {
        int s = 0;
        #pragma unroll
        for (int j = 0; j < 4; ++j) { woff[j] = s; s += wsum[j]; }
        rowptr[NN] = s;
    }
    __syncthreads();
    if (tid < NBLK) bsum[tid] = woff[wv] + (x - v);
}

__global__ void scan3_k(int* __restrict__ rowptr, const int* __restrict__ bsum) {
    int b = blockIdx.x;
    int i = b * 256 + threadIdx.x;
    if (i < NN) rowptr[i] += bsum[b];
}

// ---------------- scatter: packed (col:16 | bf16(lap):16) single 4B word per edge ----------------

__global__ void scatter_k(const int* __restrict__ ei, const float* __restrict__ w,
                          const float* __restrict__ dinv, const int* __restrict__ rowptr,
                          int* __restrict__ fill, unsigned* __restrict__ pairs,
                          const int* __restrict__ flagp) {
    int flag = *flagp;
    int e = blockIdx.x * 256 + threadIdx.x;
    if (e >= EE) return;
    int r, c; load_edge(ei, e, flag, r, c);
    if (r == c) return;
    int pos = rowptr[r] + atomicAdd(&fill[r], 1);
    float lap = -dinv[r] * dinv[c] * w[e];
    bf16 lb = (bf16)lap;
    pairs[pos] = (unsigned)c | ((unsigned)*(unsigned short*)&lb << 16);
}

// ---------------- SpMM fp8-gather: 9 threads/node, 16 fp8/edge, packed 4B edge stream ----------------

template <int MODE>
__global__ void spmm_k(const unsigned char* __restrict__ vq, const bf16* __restrict__ x0,
                       const int* __restrict__ rowptr, const unsigned* __restrict__ pairs,
                       bf16* __restrict__ y, unsigned char* __restrict__ yq) {
    int t = blockIdx.x * 256 + threadIdx.x;
    if (t >= NN * 9) return;
    int i = t / 9;
    int fo = (t - i * 9) * 16;
    const unsigned char* vp = vq + fo;

    float a[16];
    #pragma unroll
    for (int j = 0; j < 16; ++j) a[j] = 0.f;

    int s = rowptr[i], e = rowptr[i + 1];
    int p = s;
    for (; p + 1 < e; p += 2) {
        unsigned pr0 = pairs[p], pr1 = pairs[p + 1];
        uint4 u0 = *(const uint4*)(vp + (pr0 & 0xffffu) * FF);
        uint4 u1 = *(const uint4*)(vp + (pr1 & 0xffffu) * FF);
        fma16q(a, bhi(pr0), u0);
        fma16q(a, bhi(pr1), u1);
    }
    if (p < e) {
        unsigned pr = pairs[p];
        uint4 u = *(const uint4*)(vp + (pr & 0xffffu) * FF);
        fma16q(a, bhi(pr), u);
    }

    if (MODE == 1) {
        const uint4* xp = (const uint4*)((const unsigned short*)x0 + i * FF + fo);
        uint4 u0 = xp[0], u1 = xp[1];
        a[0]  = 2.f * a[0]  - blo(u0.x);  a[1]  = 2.f * a[1]  - bhi(u0.x);
        a[2]  = 2.f * a[2]  - blo(u0.y);  a[3]  = 2.f * a[3]  - bhi(u0.y);
        a[4]  = 2.f * a[4]  - blo(u0.z);  a[5]  = 2.f * a[5]  - bhi(u0.z);
        a[6]  = 2.f * a[6]  - blo(u0.w);  a[7]  = 2.f * a[7]  - bhi(u0.w);
        a[8]  = 2.f * a[8]  - blo(u1.x);  a[9]  = 2.f * a[9]  - bhi(u1.x);
        a[10] = 2.f * a[10] - blo(u1.y);  a[11] = 2.f * a[11] - bhi(u1.y);
        a[12] = 2.f * a[12] - blo(u1.z);  a[13] = 2.f * a[13] - bhi(u1.z);
        a[14] = 2.f * a[14] - blo(u1.w);  a[15] = 2.f * a[15] - bhi(u1.w);
    }

    unsigned short hs[16];
    #pragma unroll
    for (int j = 0; j < 16; ++j) {
        bf16 b = (bf16)a[j];
        hs[j] = *(unsigned short*)&b;
    }
    uint4* yp = (uint4*)((unsigned short*)y + i * FF + fo);
    yp[0] = ((uint4*)hs)[0];
    yp[1] = ((uint4*)hs)[1];

    if (MODE == 0) {
        uint4 q;
        q.x = enc4(a[0], a[1], a[2], a[3]);
        q.y = enc4(a[4], a[5], a[6], a[7]);
        q.z = enc4(a[8], a[9], a[10], a[11]);
        q.w = enc4(a[12], a[13], a[14], a[15]);
        *(uint4*)(yq + i * FF + fo) = q;
    }
}

// ---------------- fused MFMA GEMM: full W resident in LDS, 1 block/CU, 16 waves ----------------
// 3*144*168 shorts = 145,152 B LDS (< 160 KiB/CU). One barrier total.
// Grid 256 x 1024 threads. N = 50000 = 3125 tiles of 16 rows exactly.
// tile = wave*256 + blockIdx (transpose distribution -> every block has 12-13 active waves).

__global__ __launch_bounds__(1024)
void gemm_fused(const bf16* __restrict__ A0, const bf16* __restrict__ A1,
                const bf16* __restrict__ A2, const short* __restrict__ wtb,
                const float* __restrict__ bias, float* __restrict__ out) {
    __shared__ __align__(16) short Wt[3 * 144 * 168];   // 145,152 B
    int tid = threadIdx.x;

    // Stage ALL of W once: 9072 uint4 over 1024 threads = 9 iterations.
    {
        const uint4* Wg = (const uint4*)wtb;
        uint4* Wl = (uint4*)Wt;
        #pragma unroll
        for (int q = 0; q < 9; ++q) {
            int idx = q * 1024 + tid;
            if (idx < 9072) Wl[idx] = Wg[idx];
        }
    }
    __syncthreads();   // the ONLY barrier

    int wv = tid >> 6, ln = tid & 63;
    int m16 = ln & 15, quad = ln >> 4;
    int tile = wv * 256 + blockIdx.x;          // 0..4095, active < 3125
    if (tile * 16 >= NN) return;
    int rowBase = tile * 16;
    int row = rowBase + m16;                   // always < NN (50000 = 3125*16)

    const bf16* const srcs[3] = {A0, A1, A2};
    const short8 zero8 = {0, 0, 0, 0, 0, 0, 0, 0};

    floatx4 acc[9];
    #pragma unroll
    for (int q = 0; q < 9; ++q) acc[q] = (floatx4){0.f, 0.f, 0.f, 0.f};

    #pragma unroll
    for (int ph = 0; ph < 3; ++ph) {
        const bf16* A = srcs[ph];
        short8 a[5];
        #pragma unroll
        for (int kt = 0; kt < 5; ++kt) {
            int k0 = kt * 32 + quad * 8;
            if (k0 < FF)
                a[kt] = *(const short8*)((const short*)A + row * FF + k0);
            else
                a[kt] = zero8;
        }

        const short* Wp = Wt + ph * 144 * 168;
        #pragma unroll
        for (int nt = 0; nt < 9; ++nt) {
            #pragma unroll
            for (int kt = 0; kt < 5; ++kt) {
                short8 b = *(const short8*)&Wp[(nt * 16 + m16) * 168 + kt * 32 + quad * 8];
                acc[nt] = __builtin_amdgcn_mfma_f32_16x16x32_bf16(a[kt], b, acc[nt], 0, 0, 0);
            }
        }
    }

    int rowc = rowBase + quad * 4;
    #pragma unroll
    for (int nt = 0; nt < 9; ++nt) {
        int col = nt * 16 + m16;
        float bs = bias[col];
        #pragma unroll
        for (int r = 0; r < 4; ++r) {
            int rr = rowc + r;
            out[rr * FF + col] = acc[nt][r] + bs;
        }
    }
}

// ---------------- launch ----------------

extern "C" void kernel_launch(void* const* d_in, const int* in_sizes, int n_in,
                              void* d_out, int out_size, void* d_ws, size_t ws_size,
                              hipStream_t stream) {
    int ix = -1, iei = -1, iew = -1, iwt = -1, ib = -1;
    for (int i = 0; i < n_in; ++i) {
        switch (in_sizes[i]) {
            case NN * FF:      if (ix  < 0) ix  = i; break;
            case 2 * EE:       if (iei < 0) iei = i; break;
            case EE:           if (iew < 0) iew = i; break;
            case 3 * FF * FF:  if (iwt < 0) iwt = i; break;
            case FF:           if (ib  < 0) ib  = i; break;
        }
    }
    if (ix < 0 || iei < 0 || iew < 0 || iwt < 0 || ib < 0) {
        ix = 0; iei = 1; iew = 2; iwt = 3; ib = 4;
    }
    const float* x    = (const float*)d_in[ix];
    const int*   ei   = (const int*)d_in[iei];
    const float* ew   = (const float*)d_in[iew];
    const float* wt   = (const float*)d_in[iwt];
    const float* bias = (const float*)d_in[ib];
    float* out = (float*)d_out;   // reference output dtype is float32

    char* p = (char*)d_ws;
    int*      cnt    = (int*)(p + 0);           // N ints
    int*      fill   = (int*)(p + 200000);      // N ints
    int*      rowptr = (int*)(p + 400000);      // N+1 ints
    float*    dinv   = (float*)(p + 600016);    // N floats
    unsigned* pairs  = (unsigned*)(p + 800016); // E packed words (3.2 MB) -> ends 4,000,016
    bf16*     tx1    = (bf16*)(p + 7200016);
    bf16*     tx2    = (bf16*)(p + 21600016);
    short*    wtb    = (short*)(p + 36000016);  // 3*144*168 shorts
    int*      bsum   = (int*)(p + 36200000);    // NBLK ints
    unsigned char* xq   = (unsigned char*)(p + 36300000);  // N*F fp8
    unsigned char* tx1q = (unsigned char*)(p + 43600000);  // N*F fp8
    bf16*     xb     = (bf16*)(p + 64800016);
    int*      eflag  = (int*)(p + 79200016);

    if (ws_size < 79200032) return;

    hipMemsetAsync(d_ws, 0, 400000, stream);  // cnt + fill

    int ewGrid16 = (NN * FF / 16 + 255) / 256;
    int spGrid   = (NN * 9 + 255) / 256;
    int wGrid    = (3 * FF * 168 + 255) / 256;

    detect_k<<<1, 256, 0, stream>>>(ei, eflag);
    cvt_k<<<ewGrid16, 256, 0, stream>>>(x, xb, xq);
    cvtw_k<<<wGrid, 256, 0, stream>>>(wt, wtb);
    hist_k<<<(EE + 255) / 256, 256, 0, stream>>>(ei, cnt, eflag);
    scan1_k<<<NBLK, 256, 0, stream>>>(cnt, rowptr, bsum, dinv);
    scan2_k<<<1, 256, 0, stream>>>(bsum, rowptr);
    scan3_k<<<NBLK, 256, 0, stream>>>(rowptr, bsum);
    scatter_k<<<(EE + 255) / 256, 256, 0, stream>>>(ei, ew, dinv, rowptr, fill, pairs, eflag);

    spmm_k<0><<<spGrid, 256, 0, stream>>>(xq, xb, rowptr, pairs, tx1, tx1q);
    spmm_k<1><<<spGrid, 256, 0, stream>>>(tx1q, xb, rowptr, pairs, tx2, (unsigned char*)0);
    gemm_fused<<<256, 1024, 0, stream>>>(xb, tx1, tx2, wtb, bias, out);
}

// Round 2
// 218.485 us; speedup vs baseline: 1.2084x; 1.1216x over previous
//
#include <hip/hip_runtime.h>
#include <hip/hip_bf16.h>

#define NN 50000
#define EE 800000
#define FF 144
#define NBLK 196    // ceil(NN/256)
#define CVTBLK 1758 // ceil(NN*FF/16/256) = ceil(450000/256)
#define HISTBLK 3125 // EE/256

typedef __hip_bfloat16 bf16;
typedef __attribute__((ext_vector_type(8))) short short8;
typedef __attribute__((ext_vector_type(4))) float floatx4;
typedef __attribute__((ext_vector_type(2))) float float2v;

__device__ inline float blo(unsigned x) { return __uint_as_float(x << 16); }
__device__ inline float bhi(unsigned x) { return __uint_as_float(x & 0xffff0000u); }

// ---- fp8 e4m3 pack/unpack (gfx950 OCP) ----
__device__ inline void dec4fma(float* a, float l, unsigned d) {
    float2v p0 = __builtin_amdgcn_cvt_pk_f32_fp8((int)d, false);
    float2v p1 = __builtin_amdgcn_cvt_pk_f32_fp8((int)d, true);
    a[0] = fmaf(l, p0.x, a[0]);
    a[1] = fmaf(l, p0.y, a[1]);
    a[2] = fmaf(l, p1.x, a[2]);
    a[3] = fmaf(l, p1.y, a[3]);
}
__device__ inline void fma16q(float* a, float l, uint4 u) {
    dec4fma(a + 0, l, u.x);
    dec4fma(a + 4, l, u.y);
    dec4fma(a + 8, l, u.z);
    dec4fma(a + 12, l, u.w);
}
__device__ inline unsigned enc4(float a, float b, float c, float d) {
    int w = __builtin_amdgcn_cvt_pk_fp8_f32(a, b, 0, false);
    w = __builtin_amdgcn_cvt_pk_fp8_f32(c, d, w, true);
    return (unsigned)w;
}

// ---------------- edge_index int64-layout detection ----------------

__global__ void detect_k(const int* __restrict__ ei, int* __restrict__ flag) {
    __shared__ int nz;
    if (threadIdx.x == 0) nz = 0;
    __syncthreads();
    if (ei[2 * threadIdx.x + 1] != 0) atomicAdd(&nz, 1);
    __syncthreads();
    if (threadIdx.x == 0) *flag = (nz == 0) ? 1 : 0;
}

__device__ inline void load_edge(const int* ei, int e, int flag, int& r, int& c) {
    if (flag) { r = ei[2 * e]; c = ei[2 * EE + 2 * e]; }
    else      { r = ei[e];     c = ei[EE + e]; }
}

// ---------------- fused: x fp32 -> bf16 + fp8  AND  histogram+rank ----------------
// Blocks [0, CVTBLK): convert. Blocks [CVTBLK, CVTBLK+HISTBLK): histogram.
// The streaming convert work overlaps the atomic-latency-bound histogram.

__global__ void cvthist_k(const float* __restrict__ x, bf16* __restrict__ xb,
                          unsigned char* __restrict__ xq,
                          const int* __restrict__ ei, int* __restrict__ cnt,
                          unsigned char* __restrict__ rank,
                          const int* __restrict__ flagp) {
    int b = blockIdx.x;
    if (b < CVTBLK) {
        int t = b * 256 + threadIdx.x;
        if (t >= NN * FF / 16) return;
        const float4* xp = (const float4*)x + t * 4;
        float4 v0 = xp[0], v1 = xp[1], v2 = xp[2], v3 = xp[3];
        float f[16] = {v0.x, v0.y, v0.z, v0.w, v1.x, v1.y, v1.z, v1.w,
                       v2.x, v2.y, v2.z, v2.w, v3.x, v3.y, v3.z, v3.w};
        unsigned short hs[16];
        #pragma unroll
        for (int j = 0; j < 16; ++j) {
            bf16 bb = (bf16)f[j];
            hs[j] = *(unsigned short*)&bb;
        }
        uint4* xbq = (uint4*)xb + t * 2;
        xbq[0] = ((uint4*)hs)[0];
        xbq[1] = ((uint4*)hs)[1];
        uint4 q;
        q.x = enc4(f[0], f[1], f[2], f[3]);
        q.y = enc4(f[4], f[5], f[6], f[7]);
        q.z = enc4(f[8], f[9], f[10], f[11]);
        q.w = enc4(f[12], f[13], f[14], f[15]);
        ((uint4*)xq)[t] = q;
    } else {
        int flag = *flagp;
        int e = (b - CVTBLK) * 256 + threadIdx.x;
        if (e >= EE) return;
        int r, c; load_edge(ei, e, flag, r, c);
        if (r != c) rank[e] = (unsigned char)atomicAdd(&cnt[r], 1);
    }
}

// ---------------- W fp32 (K,i,o) -> bf16 transposed padded image wtb[ph][o][i] ----------------

__global__ void cvtw_k(const float* __restrict__ wt, short* __restrict__ wtb) {
    int t = blockIdx.x * 256 + threadIdx.x;
    if (t >= 3 * FF * 168) return;
    int ph = t / (FF * 168);
    int rem = t - ph * FF * 168;
    int o = rem / 168;
    int i = rem - o * 168;
    short v = 0;
    if (i < FF) {
        bf16 b = (bf16)wt[ph * FF * FF + i * FF + o];
        v = *(const short*)&b;
    }
    wtb[t] = v;
}

// ---------------- multi-block exclusive scan (dinv fused into phase 1) ----------------

__global__ void scan1_k(const int* __restrict__ cnt, int* __restrict__ rowptr,
                        int* __restrict__ bsum, float* __restrict__ dinv) {
    __shared__ int wsum[4], woff[4];
    int b = blockIdx.x, tid = threadIdx.x;
    int wv = tid >> 6, ln = tid & 63;
    int i = b * 256 + tid;
    int v = (i < NN) ? cnt[i] : 0;
    if (i < NN) dinv[i] = v > 0 ? rsqrtf((float)v) : 0.f;
    int x = v;
    #pragma unroll
    for (int off = 1; off < 64; off <<= 1) {
        int t = __shfl_up(x, off, 64);
        if (ln >= off) x += t;
    }
    if (ln == 63) wsum[wv] = x;
    __syncthreads();
    if (tid == 0) {
        int s = 0;
        #pragma unroll
        for (int j = 0; j < 4; ++j) { woff[j] = s; s += wsum[j]; }
        bsum[b] = s;
    }
    __syncthreads();
    if (i < NN) rowptr[i] = woff[wv] + (x - v);
}

__global__ void scan2_k(int* __restrict__ bsum, int* __restrict__ rowptr) {
    __shared__ int wsum[4], woff[4];
    int tid = threadIdx.x;
    int wv = tid >> 6, ln = tid & 63;
    int v = (tid < NBLK) ? bsum[tid] : 0;
    int x = v;
    #pragma unroll
    for (int off = 1; off < 64; off <<= 1) {
        int t = __shfl_up(x, off, 64);
        if (ln >= off) x += t;
    }
    if (ln == 63) wsum[wv] = x;
    __syncthreads();
    if (tid == 0) {
        int s = 0;
        #pragma unroll
        for (int j = 0; j < 4; ++j) { woff[j] = s; s += wsum[j]; }
        rowptr[NN] = s;
    }
    __syncthreads();
    if (tid < NBLK) bsum[tid] = woff[wv] + (x - v);
}

__global__ void scan3_k(int* __restrict__ rowptr, const int* __restrict__ bsum) {
    int b = blockIdx.x;
    int i = b * 256 + threadIdx.x;
    if (i < NN) rowptr[i] += bsum[b];
}

// ---------------- scatter: NO atomics — pos = rowptr[r] + rank[e] ----------------
// packed (col:16 | bf16(lap):16) single 4B word per edge

__global__ void scatter_k(const int* __restrict__ ei, const float* __restrict__ w,
                          const float* __restrict__ dinv, const int* __restrict__ rowptr,
                          const unsigned char* __restrict__ rank,
                          unsigned* __restrict__ pairs, const int* __restrict__ flagp) {
    int flag = *flagp;
    int e = blockIdx.x * 256 + threadIdx.x;
    if (e >= EE) return;
    int r, c; load_edge(ei, e, flag, r, c);
    if (r == c) return;
    int pos = rowptr[r] + (int)rank[e];
    float lap = -dinv[r] * dinv[c] * w[e];
    bf16 lb = (bf16)lap;
    pairs[pos] = (unsigned)c | ((unsigned)*(unsigned short*)&lb << 16);
}

// ---------------- SpMM fp8-gather: 9 threads/node, 16 fp8/edge, packed 4B edge stream ----------------

template <int MODE>
__global__ void spmm_k(const unsigned char* __restrict__ vq, const bf16* __restrict__ x0,
                       const int* __restrict__ rowptr, const unsigned* __restrict__ pairs,
                       bf16* __restrict__ y, unsigned char* __restrict__ yq) {
    int t = blockIdx.x * 256 + threadIdx.x;
    if (t >= NN * 9) return;
    int i = t / 9;
    int fo = (t - i * 9) * 16;
    const unsigned char* vp = vq + fo;

    float a[16];
    #pragma unroll
    for (int j = 0; j < 16; ++j) a[j] = 0.f;

    int s = rowptr[i], e = rowptr[i + 1];
    int p = s;
    for (; p + 1 < e; p += 2) {
        unsigned pr0 = pairs[p], pr1 = pairs[p + 1];
        uint4 u0 = *(const uint4*)(vp + (pr0 & 0xffffu) * FF);
        uint4 u1 = *(const uint4*)(vp + (pr1 & 0xffffu) * FF);
        fma16q(a, bhi(pr0), u0);
        fma16q(a, bhi(pr1), u1);
    }
    if (p < e) {
        unsigned pr = pairs[p];
        uint4 u = *(const uint4*)(vp + (pr & 0xffffu) * FF);
        fma16q(a, bhi(pr), u);
    }

    if (MODE == 1) {
        const uint4* xp = (const uint4*)((const unsigned short*)x0 + i * FF + fo);
        uint4 u0 = xp[0], u1 = xp[1];
        a[0]  = 2.f * a[0]  - blo(u0.x);  a[1]  = 2.f * a[1]  - bhi(u0.x);
        a[2]  = 2.f * a[2]  - blo(u0.y);  a[3]  = 2.f * a[3]  - bhi(u0.y);
        a[4]  = 2.f * a[4]  - blo(u0.z);  a[5]  = 2.f * a[5]  - bhi(u0.z);
        a[6]  = 2.f * a[6]  - blo(u0.w);  a[7]  = 2.f * a[7]  - bhi(u0.w);
        a[8]  = 2.f * a[8]  - blo(u1.x);  a[9]  = 2.f * a[9]  - bhi(u1.x);
        a[10] = 2.f * a[10] - blo(u1.y);  a[11] = 2.f * a[11] - bhi(u1.y);
        a[12] = 2.f * a[12] - blo(u1.z);  a[13] = 2.f * a[13] - bhi(u1.z);
        a[14] = 2.f * a[14] - blo(u1.w);  a[15] = 2.f * a[15] - bhi(u1.w);
    }

    unsigned short hs[16];
    #pragma unroll
    for (int j = 0; j < 16; ++j) {
        bf16 b = (bf16)a[j];
        hs[j] = *(unsigned short*)&b;
    }
    uint4* yp = (uint4*)((unsigned short*)y + i * FF + fo);
    yp[0] = ((uint4*)hs)[0];
    yp[1] = ((uint4*)hs)[1];

    if (MODE == 0) {
        uint4 q;
        q.x = enc4(a[0], a[1], a[2], a[3]);
        q.y = enc4(a[4], a[5], a[6], a[7]);
        q.z = enc4(a[8], a[9], a[10], a[11]);
        q.w = enc4(a[12], a[13], a[14], a[15]);
        *(uint4*)(yq + i * FF + fo) = q;
    }
}

// ---------------- fused MFMA GEMM: full W resident in LDS, 1 block/CU, 16 waves ----------------
// 3*144*168 shorts = 145,152 B LDS (< 160 KiB/CU). One barrier total.
// Grid 256 x 1024 threads. N = 50000 = 3125 tiles of 16 rows exactly.
// tile = wave*256 + blockIdx (transpose distribution -> every block has 12-13 active waves).

__global__ __launch_bounds__(1024)
void gemm_fused(const bf16* __restrict__ A0, const bf16* __restrict__ A1,
                const bf16* __restrict__ A2, const short* __restrict__ wtb,
                const float* __restrict__ bias, float* __restrict__ out) {
    __shared__ __align__(16) short Wt[3 * 144 * 168];   // 145,152 B
    int tid = threadIdx.x;

    // Stage ALL of W once: 9072 uint4 over 1024 threads = 9 iterations.
    {
        const uint4* Wg = (const uint4*)wtb;
        uint4* Wl = (uint4*)Wt;
        #pragma unroll
        for (int q = 0; q < 9; ++q) {
            int idx = q * 1024 + tid;
            if (idx < 9072) Wl[idx] = Wg[idx];
        }
    }
    __syncthreads();   // the ONLY barrier

    int wv = tid >> 6, ln = tid & 63;
    int m16 = ln & 15, quad = ln >> 4;
    int tile = wv * 256 + blockIdx.x;          // 0..4095, active < 3125
    if (tile * 16 >= NN) return;
    int rowBase = tile * 16;
    int row = rowBase + m16;                   // always < NN (50000 = 3125*16)

    const bf16* const srcs[3] = {A0, A1, A2};
    const short8 zero8 = {0, 0, 0, 0, 0, 0, 0, 0};

    floatx4 acc[9];
    #pragma unroll
    for (int q = 0; q < 9; ++q) acc[q] = (floatx4){0.f, 0.f, 0.f, 0.f};

    #pragma unroll
    for (int ph = 0; ph < 3; ++ph) {
        const bf16* A = srcs[ph];
        short8 a[5];
        #pragma unroll
        for (int kt = 0; kt < 5; ++kt) {
            int k0 = kt * 32 + quad * 8;
            if (k0 < FF)
                a[kt] = *(const short8*)((const short*)A + row * FF + k0);
            else
                a[kt] = zero8;
        }

        const short* Wp = Wt + ph * 144 * 168;
        #pragma unroll
        for (int nt = 0; nt < 9; ++nt) {
            #pragma unroll
            for (int kt = 0; kt < 5; ++kt) {
                short8 b = *(const short8*)&Wp[(nt * 16 + m16) * 168 + kt * 32 + quad * 8];
                acc[nt] = __builtin_amdgcn_mfma_f32_16x16x32_bf16(a[kt], b, acc[nt], 0, 0, 0);
            }
        }
    }

    int rowc = rowBase + quad * 4;
    #pragma unroll
    for (int nt = 0; nt < 9; ++nt) {
        int col = nt * 16 + m16;
        float bs = bias[col];
        #pragma unroll
        for (int r = 0; r < 4; ++r) {
            int rr = rowc + r;
            out[rr * FF + col] = acc[nt][r] + bs;
        }
    }
}

// ---------------- launch ----------------

extern "C" void kernel_launch(void* const* d_in, const int* in_sizes, int n_in,
                              void* d_out, int out_size, void* d_ws, size_t ws_size,
                              hipStream_t stream) {
    int ix = -1, iei = -1, iew = -1, iwt = -1, ib = -1;
    for (int i = 0; i < n_in; ++i) {
        switch (in_sizes[i]) {
            case NN * FF:      if (ix  < 0) ix  = i; break;
            case 2 * EE:       if (iei < 0) iei = i; break;
            case EE:           if (iew < 0) iew = i; break;
            case 3 * FF * FF:  if (iwt < 0) iwt = i; break;
            case FF:           if (ib  < 0) ib  = i; break;
        }
    }
    if (ix < 0 || iei < 0 || iew < 0 || iwt < 0 || ib < 0) {
        ix = 0; iei = 1; iew = 2; iwt = 3; ib = 4;
    }
    const float* x    = (const float*)d_in[ix];
    const int*   ei   = (const int*)d_in[iei];
    const float* ew   = (const float*)d_in[iew];
    const float* wt   = (const float*)d_in[iwt];
    const float* bias = (const float*)d_in[ib];
    float* out = (float*)d_out;   // reference output dtype is float32

    char* p = (char*)d_ws;
    int*      cnt    = (int*)(p + 0);           // N ints
    int*      rowptr = (int*)(p + 400000);      // N+1 ints
    float*    dinv   = (float*)(p + 600016);    // N floats
    unsigned* pairs  = (unsigned*)(p + 800016); // E packed words (3.2 MB) -> ends 4,000,016
    unsigned char* rank = (unsigned char*)(p + 4000016); // E bytes -> ends 4,800,016
    bf16*     tx1    = (bf16*)(p + 7200016);
    bf16*     tx2    = (bf16*)(p + 21600016);
    short*    wtb    = (short*)(p + 36000016);  // 3*144*168 shorts
    int*      bsum   = (int*)(p + 36200000);    // NBLK ints
    unsigned char* xq   = (unsigned char*)(p + 36300000);  // N*F fp8
    unsigned char* tx1q = (unsigned char*)(p + 43600000);  // N*F fp8
    bf16*     xb     = (bf16*)(p + 64800016);
    int*      eflag  = (int*)(p + 79200016);

    if (ws_size < 79200032) return;

    hipMemsetAsync(d_ws, 0, 200000, stream);  // cnt only

    int spGrid   = (NN * 9 + 255) / 256;
    int wGrid    = (3 * FF * 168 + 255) / 256;

    detect_k<<<1, 256, 0, stream>>>(ei, eflag);
    cvthist_k<<<CVTBLK + HISTBLK, 256, 0, stream>>>(x, xb, xq, ei, cnt, rank, eflag);
    cvtw_k<<<wGrid, 256, 0, stream>>>(wt, wtb);
    scan1_k<<<NBLK, 256, 0, stream>>>(cnt, rowptr, bsum, dinv);
    scan2_k<<<1, 256, 0, stream>>>(bsum, rowptr);
    scan3_k<<<NBLK, 256, 0, stream>>>(rowptr, bsum);
    scatter_k<<<(EE + 255) / 256, 256, 0, stream>>>(ei, ew, dinv, rowptr, rank, pairs, eflag);

    spmm_k<0><<<spGrid, 256, 0, stream>>>(xq, xb, rowptr, pairs, tx1, tx1q);
    spmm_k<1><<<spGrid, 256, 0, stream>>>(tx1q, xb, rowptr, pairs, tx2, (unsigned char*)0);
    gemm_fused<<<256, 1024, 0, stream>>>(xb, tx1, tx2, wtb, bias, out);
}

// Round 3
// 216.734 us; speedup vs baseline: 1.2181x; 1.0081x over previous
//
#include <hip/hip_runtime.h>
#include <hip/hip_bf16.h>

#define NN 50000
#define EE 800000
#define FF 144
#define NBLK 196    // ceil(NN/256)
#define CVTBLK 1758 // ceil(NN*FF/16/256) = ceil(450000/256)
#define HISTBLK 3125 // EE/256
#define CSTRIDE 16  // counter pad: 16 ints = 64B line per counter

typedef __hip_bfloat16 bf16;
typedef __attribute__((ext_vector_type(8))) short short8;
typedef __attribute__((ext_vector_type(4))) float floatx4;
typedef __attribute__((ext_vector_type(2))) float float2v;

__device__ inline float blo(unsigned x) { return __uint_as_float(x << 16); }
__device__ inline float bhi(unsigned x) { return __uint_as_float(x & 0xffff0000u); }

// ---- fp8 e4m3 pack/unpack (gfx950 OCP) ----
__device__ inline void dec4fma(float* a, float l, unsigned d) {
    float2v p0 = __builtin_amdgcn_cvt_pk_f32_fp8((int)d, false);
    float2v p1 = __builtin_amdgcn_cvt_pk_f32_fp8((int)d, true);
    a[0] = fmaf(l, p0.x, a[0]);
    a[1] = fmaf(l, p0.y, a[1]);
    a[2] = fmaf(l, p1.x, a[2]);
    a[3] = fmaf(l, p1.y, a[3]);
}
__device__ inline void fma16q(float* a, float l, uint4 u) {
    dec4fma(a + 0, l, u.x);
    dec4fma(a + 4, l, u.y);
    dec4fma(a + 8, l, u.z);
    dec4fma(a + 12, l, u.w);
}
__device__ inline unsigned enc4(float a, float b, float c, float d) {
    int w = __builtin_amdgcn_cvt_pk_fp8_f32(a, b, 0, false);
    w = __builtin_amdgcn_cvt_pk_fp8_f32(c, d, w, true);
    return (unsigned)w;
}

// ---------------- edge_index int64-layout detection ----------------

__global__ void detect_k(const int* __restrict__ ei, int* __restrict__ flag) {
    __shared__ int nz;
    if (threadIdx.x == 0) nz = 0;
    __syncthreads();
    if (ei[2 * threadIdx.x + 1] != 0) atomicAdd(&nz, 1);
    __syncthreads();
    if (threadIdx.x == 0) *flag = (nz == 0) ? 1 : 0;
}

__device__ inline void load_edge(const int* ei, int e, int flag, int& r, int& c) {
    if (flag) { r = ei[2 * e]; c = ei[2 * EE + 2 * e]; }
    else      { r = ei[e];     c = ei[EE + e]; }
}

// ---------------- fused: x fp32 -> bf16 + fp8  AND  histogram+rank ----------------
// Blocks [0, CVTBLK): convert. Blocks [CVTBLK, CVTBLK+HISTBLK): histogram.
// Counters padded to one 64B line each: spreads same-line atomic serialization 16x.

__global__ void cvthist_k(const float* __restrict__ x, bf16* __restrict__ xb,
                          unsigned char* __restrict__ xq,
                          const int* __restrict__ ei, int* __restrict__ cnt,
                          unsigned char* __restrict__ rank,
                          const int* __restrict__ flagp) {
    int b = blockIdx.x;
    if (b < CVTBLK) {
        int t = b * 256 + threadIdx.x;
        if (t >= NN * FF / 16) return;
        const float4* xp = (const float4*)x + t * 4;
        float4 v0 = xp[0], v1 = xp[1], v2 = xp[2], v3 = xp[3];
        float f[16] = {v0.x, v0.y, v0.z, v0.w, v1.x, v1.y, v1.z, v1.w,
                       v2.x, v2.y, v2.z, v2.w, v3.x, v3.y, v3.z, v3.w};
        unsigned short hs[16];
        #pragma unroll
        for (int j = 0; j < 16; ++j) {
            bf16 bb = (bf16)f[j];
            hs[j] = *(unsigned short*)&bb;
        }
        uint4* xbq = (uint4*)xb + t * 2;
        xbq[0] = ((uint4*)hs)[0];
        xbq[1] = ((uint4*)hs)[1];
        uint4 q;
        q.x = enc4(f[0], f[1], f[2], f[3]);
        q.y = enc4(f[4], f[5], f[6], f[7]);
        q.z = enc4(f[8], f[9], f[10], f[11]);
        q.w = enc4(f[12], f[13], f[14], f[15]);
        ((uint4*)xq)[t] = q;
    } else {
        int flag = *flagp;
        int e = (b - CVTBLK) * 256 + threadIdx.x;
        if (e >= EE) return;
        int r, c; load_edge(ei, e, flag, r, c);
        if (r != c) rank[e] = (unsigned char)atomicAdd(&cnt[r * CSTRIDE], 1);
    }
}

// ---------------- W fp32 (K,i,o) -> bf16 transposed padded image wtb[ph][o][i] ----------------

__global__ void cvtw_k(const float* __restrict__ wt, short* __restrict__ wtb) {
    int t = blockIdx.x * 256 + threadIdx.x;
    if (t >= 3 * FF * 168) return;
    int ph = t / (FF * 168);
    int rem = t - ph * FF * 168;
    int o = rem / 168;
    int i = rem - o * 168;
    short v = 0;
    if (i < FF) {
        bf16 b = (bf16)wt[ph * FF * FF + i * FF + o];
        v = *(const short*)&b;
    }
    wtb[t] = v;
}

// ---------------- multi-block exclusive scan (dinv fused into phase 1) ----------------

__global__ void scan1_k(const int* __restrict__ cnt, int* __restrict__ rowptr,
                        int* __restrict__ bsum, float* __restrict__ dinv) {
    __shared__ int wsum[4], woff[4];
    int b = blockIdx.x, tid = threadIdx.x;
    int wv = tid >> 6, ln = tid & 63;
    int i = b * 256 + tid;
    int v = (i < NN) ? cnt[i * CSTRIDE] : 0;
    if (i < NN) dinv[i] = v > 0 ? rsqrtf((float)v) : 0.f;
    int x = v;
    #pragma unroll
    for (int off = 1; off < 64; off <<= 1) {
        int t = __shfl_up(x, off, 64);
        if (ln >= off) x += t;
    }
    if (ln == 63) wsum[wv] = x;
    __syncthreads();
    if (tid == 0) {
        int s = 0;
        #pragma unroll
        for (int j = 0; j < 4; ++j) { woff[j] = s; s += wsum[j]; }
        bsum[b] = s;
    }
    __syncthreads();
    if (i < NN) rowptr[i] = woff[wv] + (x - v);
}

__global__ void scan2_k(int* __restrict__ bsum, int* __restrict__ rowptr) {
    __shared__ int wsum[4], woff[4];
    int tid = threadIdx.x;
    int wv = tid >> 6, ln = tid & 63;
    int v = (tid < NBLK) ? bsum[tid] : 0;
    int x = v;
    #pragma unroll
    for (int off = 1; off < 64; off <<= 1) {
        int t = __shfl_up(x, off, 64);
        if (ln >= off) x += t;
    }
    if (ln == 63) wsum[wv] = x;
    __syncthreads();
    if (tid == 0) {
        int s = 0;
        #pragma unroll
        for (int j = 0; j < 4; ++j) { woff[j] = s; s += wsum[j]; }
        rowptr[NN] = s;
    }
    __syncthreads();
    if (tid < NBLK) bsum[tid] = woff[wv] + (x - v);
}

__global__ void scan3_k(int* __restrict__ rowptr, const int* __restrict__ bsum) {
    int b = blockIdx.x;
    int i = b * 256 + threadIdx.x;
    if (i < NN) rowptr[i] += bsum[b];
}

// ---------------- scatter: NO atomics — pos = rowptr[r] + rank[e] ----------------
// packed (col:16 | bf16(lap):16) single 4B word per edge

__global__ void scatter_k(const int* __restrict__ ei, const float* __restrict__ w,
                          const float* __restrict__ dinv, const int* __restrict__ rowptr,
                          const unsigned char* __restrict__ rank,
                          unsigned* __restrict__ pairs, const int* __restrict__ flagp) {
    int flag = *flagp;
    int e = blockIdx.x * 256 + threadIdx.x;
    if (e >= EE) return;
    int r, c; load_edge(ei, e, flag, r, c);
    if (r == c) return;
    int pos = rowptr[r] + (int)rank[e];
    float lap = -dinv[r] * dinv[c] * w[e];
    bf16 lb = (bf16)lap;
    pairs[pos] = (unsigned)c | ((unsigned)*(unsigned short*)&lb << 16);
}

// ---------------- SpMM fp8-gather: 9 threads/node, 16 fp8/edge, packed 4B edge stream ----------------

template <int MODE>
__global__ void spmm_k(const unsigned char* __restrict__ vq, const bf16* __restrict__ x0,
                       const int* __restrict__ rowptr, const unsigned* __restrict__ pairs,
                       bf16* __restrict__ y, unsigned char* __restrict__ yq) {
    int t = blockIdx.x * 256 + threadIdx.x;
    if (t >= NN * 9) return;
    int i = t / 9;
    int fo = (t - i * 9) * 16;
    const unsigned char* vp = vq + fo;

    float a[16];
    #pragma unroll
    for (int j = 0; j < 16; ++j) a[j] = 0.f;

    int s = rowptr[i], e = rowptr[i + 1];
    int p = s;
    for (; p + 1 < e; p += 2) {
        unsigned pr0 = pairs[p], pr1 = pairs[p + 1];
        uint4 u0 = *(const uint4*)(vp + (pr0 & 0xffffu) * FF);
        uint4 u1 = *(const uint4*)(vp + (pr1 & 0xffffu) * FF);
        fma16q(a, bhi(pr0), u0);
        fma16q(a, bhi(pr1), u1);
    }
    if (p < e) {
        unsigned pr = pairs[p];
        uint4 u = *(const uint4*)(vp + (pr & 0xffffu) * FF);
        fma16q(a, bhi(pr), u);
    }

    if (MODE == 1) {
        const uint4* xp = (const uint4*)((const unsigned short*)x0 + i * FF + fo);
        uint4 u0 = xp[0], u1 = xp[1];
        a[0]  = 2.f * a[0]  - blo(u0.x);  a[1]  = 2.f * a[1]  - bhi(u0.x);
        a[2]  = 2.f * a[2]  - blo(u0.y);  a[3]  = 2.f * a[3]  - bhi(u0.y);
        a[4]  = 2.f * a[4]  - blo(u0.z);  a[5]  = 2.f * a[5]  - bhi(u0.z);
        a[6]  = 2.f * a[6]  - blo(u0.w);  a[7]  = 2.f * a[7]  - bhi(u0.w);
        a[8]  = 2.f * a[8]  - blo(u1.x);  a[9]  = 2.f * a[9]  - bhi(u1.x);
        a[10] = 2.f * a[10] - blo(u1.y);  a[11] = 2.f * a[11] - bhi(u1.y);
        a[12] = 2.f * a[12] - blo(u1.z);  a[13] = 2.f * a[13] - bhi(u1.z);
        a[14] = 2.f * a[14] - blo(u1.w);  a[15] = 2.f * a[15] - bhi(u1.w);
    }

    unsigned short hs[16];
    #pragma unroll
    for (int j = 0; j < 16; ++j) {
        bf16 b = (bf16)a[j];
        hs[j] = *(unsigned short*)&b;
    }
    uint4* yp = (uint4*)((unsigned short*)y + i * FF + fo);
    yp[0] = ((uint4*)hs)[0];
    yp[1] = ((uint4*)hs)[1];

    if (MODE == 0) {
        uint4 q;
        q.x = enc4(a[0], a[1], a[2], a[3]);
        q.y = enc4(a[4], a[5], a[6], a[7]);
        q.z = enc4(a[8], a[9], a[10], a[11]);
        q.w = enc4(a[12], a[13], a[14], a[15]);
        *(uint4*)(yq + i * FF + fo) = q;
    }
}

// ---------------- fused MFMA GEMM: full W resident in LDS, 1 block/CU, 16 waves ----------------
// 3*144*168 shorts = 145,152 B LDS (< 160 KiB/CU). One barrier total.
// Grid 256 x 1024 threads. N = 50000 = 3125 tiles of 16 rows exactly.
// tile = wave*256 + blockIdx (transpose distribution -> every block has 12-13 active waves).

__global__ __launch_bounds__(1024)
void gemm_fused(const bf16* __restrict__ A0, const bf16* __restrict__ A1,
                const bf16* __restrict__ A2, const short* __restrict__ wtb,
                const float* __restrict__ bias, float* __restrict__ out) {
    __shared__ __align__(16) short Wt[3 * 144 * 168];   // 145,152 B
    int tid = threadIdx.x;

    // Stage ALL of W once: 9072 uint4 over 1024 threads = 9 iterations.
    {
        const uint4* Wg = (const uint4*)wtb;
        uint4* Wl = (uint4*)Wt;
        #pragma unroll
        for (int q = 0; q < 9; ++q) {
            int idx = q * 1024 + tid;
            if (idx < 9072) Wl[idx] = Wg[idx];
        }
    }
    __syncthreads();   // the ONLY barrier

    int wv = tid >> 6, ln = tid & 63;
    int m16 = ln & 15, quad = ln >> 4;
    int tile = wv * 256 + blockIdx.x;          // 0..4095, active < 3125
    if (tile * 16 >= NN) return;
    int rowBase = tile * 16;
    int row = rowBase + m16;                   // always < NN (50000 = 3125*16)

    const bf16* const srcs[3] = {A0, A1, A2};
    const short8 zero8 = {0, 0, 0, 0, 0, 0, 0, 0};

    floatx4 acc[9];
    #pragma unroll
    for (int q = 0; q < 9; ++q) acc[q] = (floatx4){0.f, 0.f, 0.f, 0.f};

    #pragma unroll
    for (int ph = 0; ph < 3; ++ph) {
        const bf16* A = srcs[ph];
        short8 a[5];
        #pragma unroll
        for (int kt = 0; kt < 5; ++kt) {
            int k0 = kt * 32 + quad * 8;
            if (k0 < FF)
                a[kt] = *(const short8*)((const short*)A + row * FF + k0);
            else
                a[kt] = zero8;
        }

        const short* Wp = Wt + ph * 144 * 168;
        #pragma unroll
        for (int nt = 0; nt < 9; ++nt) {
            #pragma unroll
            for (int kt = 0; kt < 5; ++kt) {
                short8 b = *(const short8*)&Wp[(nt * 16 + m16) * 168 + kt * 32 + quad * 8];
                acc[nt] = __builtin_amdgcn_mfma_f32_16x16x32_bf16(a[kt], b, acc[nt], 0, 0, 0);
            }
        }
    }

    int rowc = rowBase + quad * 4;
    #pragma unroll
    for (int nt = 0; nt < 9; ++nt) {
        int col = nt * 16 + m16;
        float bs = bias[col];
        #pragma unroll
        for (int r = 0; r < 4; ++r) {
            int rr = rowc + r;
            out[rr * FF + col] = acc[nt][r] + bs;
        }
    }
}

// ---------------- launch ----------------

extern "C" void kernel_launch(void* const* d_in, const int* in_sizes, int n_in,
                              void* d_out, int out_size, void* d_ws, size_t ws_size,
                              hipStream_t stream) {
    int ix = -1, iei = -1, iew = -1, iwt = -1, ib = -1;
    for (int i = 0; i < n_in; ++i) {
        switch (in_sizes[i]) {
            case NN * FF:      if (ix  < 0) ix  = i; break;
            case 2 * EE:       if (iei < 0) iei = i; break;
            case EE:           if (iew < 0) iew = i; break;
            case 3 * FF * FF:  if (iwt < 0) iwt = i; break;
            case FF:           if (ib  < 0) ib  = i; break;
        }
    }
    if (ix < 0 || iei < 0 || iew < 0 || iwt < 0 || ib < 0) {
        ix = 0; iei = 1; iew = 2; iwt = 3; ib = 4;
    }
    const float* x    = (const float*)d_in[ix];
    const int*   ei   = (const int*)d_in[iei];
    const float* ew   = (const float*)d_in[iew];
    const float* wt   = (const float*)d_in[iwt];
    const float* bias = (const float*)d_in[ib];
    float* out = (float*)d_out;   // reference output dtype is float32

    // Workspace layout (62.2 MB):
    //   cntpad [0 .. 3.2M)  (50000 x 64B) -- dead after scan1_k; pairs REUSES this region
    //   rowptr [3.2M .. 3.400004M), dinv [3.400016 .. 3.600016), bsum [3.600016+..]
    //   rank [3.7M .. 4.5M), eflag [4.5M), wtb [4.6M ..], tx1/tx2/xq/tx1q/xb after.
    char* p = (char*)d_ws;
    int*      cnt    = (int*)(p + 0);                    // 50000*16 ints = 3.2 MB
    unsigned* pairs  = (unsigned*)(p + 0);               // E words = 3.2 MB (reuse after scan)
    int*      rowptr = (int*)(p + 3200000);              // N+1 ints
    float*    dinv   = (float*)(p + 3400016);            // N floats
    int*      bsum   = (int*)(p + 3600016);              // NBLK ints
    unsigned char* rank = (unsigned char*)(p + 3700000); // E bytes
    int*      eflag  = (int*)(p + 4500000);
    short*    wtb    = (short*)(p + 4600000);            // 3*144*168 shorts = 145,152 B
    bf16*     tx1    = (bf16*)(p + 4800000);             // 14.4 MB
    bf16*     tx2    = (bf16*)(p + 19200000);            // 14.4 MB
    unsigned char* xq   = (unsigned char*)(p + 33600000); // 7.2 MB
    unsigned char* tx1q = (unsigned char*)(p + 40800000); // 7.2 MB
    bf16*     xb     = (bf16*)(p + 48000000);            // 14.4 MB -> ends 62,400,000

    if (ws_size < 62400000) return;

    hipMemsetAsync(d_ws, 0, 3200000, stream);  // padded cnt

    int spGrid   = (NN * 9 + 255) / 256;
    int wGrid    = (3 * FF * 168 + 255) / 256;

    detect_k<<<1, 256, 0, stream>>>(ei, eflag);
    cvthist_k<<<CVTBLK + HISTBLK, 256, 0, stream>>>(x, xb, xq, ei, cnt, rank, eflag);
    cvtw_k<<<wGrid, 256, 0, stream>>>(wt, wtb);
    scan1_k<<<NBLK, 256, 0, stream>>>(cnt, rowptr, bsum, dinv);
    scan2_k<<<1, 256, 0, stream>>>(bsum, rowptr);
    scan3_k<<<NBLK, 256, 0, stream>>>(rowptr, bsum);
    scatter_k<<<(EE + 255) / 256, 256, 0, stream>>>(ei, ew, dinv, rowptr, rank, pairs, eflag);

    spmm_k<0><<<spGrid, 256, 0, stream>>>(xq, xb, rowptr, pairs, tx1, tx1q);
    spmm_k<1><<<spGrid, 256, 0, stream>>>(tx1q, xb, rowptr, pairs, tx2, (unsigned char*)0);
    gemm_fused<<<256, 1024, 0, stream>>>(xb, tx1, tx2, wtb, bias, out);
}

// Round 4
// 189.036 us; speedup vs baseline: 1.3966x; 1.1465x over previous
//
#include <hip/hip_runtime.h>
#include <hip/hip_bf16.h>

#define NN 50000
#define EE 800000
#define FF 144
#define CVTBLK 1758      // ceil(NN*FF/16/256)
#define ECHK 2048        // edges per partition block
#define NBE 391          // ceil(EE/ECHK)
#define NBKT_REAL 391    // row buckets of 128 rows (covers 50048)
#define NBUCKET 392      // + 1 self-loop bucket
#define WGRID 284        // ceil(3*144*168/256)
#define HM (NBUCKET * NBE)   // 153272 histogram entries
#define SCANBLK 599      // ceil(HM/256)

typedef __hip_bfloat16 bf16;
typedef __attribute__((ext_vector_type(8))) short short8;
typedef __attribute__((ext_vector_type(4))) float floatx4;
typedef __attribute__((ext_vector_type(2))) float float2v;

__device__ inline float blo(unsigned x) { return __uint_as_float(x << 16); }
__device__ inline float bhi(unsigned x) { return __uint_as_float(x & 0xffff0000u); }

// ---- fp8 e4m3 pack/unpack (gfx950 OCP) ----
__device__ inline void dec4fma(float* a, float l, unsigned d) {
    float2v p0 = __builtin_amdgcn_cvt_pk_f32_fp8((int)d, false);
    float2v p1 = __builtin_amdgcn_cvt_pk_f32_fp8((int)d, true);
    a[0] = fmaf(l, p0.x, a[0]);
    a[1] = fmaf(l, p0.y, a[1]);
    a[2] = fmaf(l, p1.x, a[2]);
    a[3] = fmaf(l, p1.y, a[3]);
}
__device__ inline void fma16q(float* a, float l, uint4 u) {
    dec4fma(a + 0, l, u.x);
    dec4fma(a + 4, l, u.y);
    dec4fma(a + 8, l, u.z);
    dec4fma(a + 12, l, u.w);
}
__device__ inline unsigned enc4(float a, float b, float c, float d) {
    int w = __builtin_amdgcn_cvt_pk_fp8_f32(a, b, 0, false);
    w = __builtin_amdgcn_cvt_pk_fp8_f32(c, d, w, true);
    return (unsigned)w;
}

// ---------------- edge_index int64-layout detection ----------------

__global__ void detect_k(const int* __restrict__ ei, int* __restrict__ flag) {
    __shared__ int nz;
    if (threadIdx.x == 0) nz = 0;
    __syncthreads();
    if (ei[2 * threadIdx.x + 1] != 0) atomicAdd(&nz, 1);
    __syncthreads();
    if (threadIdx.x == 0) *flag = (nz == 0) ? 1 : 0;
}

__device__ inline void load_edge(const int* ei, int e, int flag, int& r, int& c) {
    if (flag) { r = ei[2 * e]; c = ei[2 * EE + 2 * e]; }
    else      { r = ei[e];     c = ei[EE + e]; }
}

// ---------------- fused A: cvt(x) | pack+bucket-hist(edges) | cvt(W) ----------------
// Blocks [0,CVTBLK): x fp32 -> bf16 + fp8.
// Blocks [CVTBLK, +NBE): pack edges into u64 items {row:16|col:16|w_fp32:32},
//   LDS histogram over 392 row-buckets (bucket = row>>7; self-loops -> 391).
// Blocks [CVTBLK+NBE, +WGRID): W fp32 -> bf16 transposed padded wtb[ph][o][i].
// ZERO global atomics anywhere in this pipeline.

__global__ void fusedA_k(const float* __restrict__ x, bf16* __restrict__ xb,
                         unsigned char* __restrict__ xq,
                         const int* __restrict__ ei, const float* __restrict__ ew,
                         unsigned long long* __restrict__ items, int* __restrict__ hist,
                         const float* __restrict__ wt, short* __restrict__ wtb,
                         const int* __restrict__ flagp) {
    __shared__ int lh[NBUCKET];
    int b = blockIdx.x;
    int tid = threadIdx.x;
    if (b < CVTBLK) {
        int t = b * 256 + tid;
        if (t >= NN * FF / 16) return;
        const float4* xp = (const float4*)x + t * 4;
        float4 v0 = xp[0], v1 = xp[1], v2 = xp[2], v3 = xp[3];
        float f[16] = {v0.x, v0.y, v0.z, v0.w, v1.x, v1.y, v1.z, v1.w,
                       v2.x, v2.y, v2.z, v2.w, v3.x, v3.y, v3.z, v3.w};
        unsigned short hs[16];
        #pragma unroll
        for (int j = 0; j < 16; ++j) {
            bf16 bb = (bf16)f[j];
            hs[j] = *(unsigned short*)&bb;
        }
        uint4* xbq = (uint4*)xb + t * 2;
        xbq[0] = ((uint4*)hs)[0];
        xbq[1] = ((uint4*)hs)[1];
        uint4 q;
        q.x = enc4(f[0], f[1], f[2], f[3]);
        q.y = enc4(f[4], f[5], f[6], f[7]);
        q.z = enc4(f[8], f[9], f[10], f[11]);
        q.w = enc4(f[12], f[13], f[14], f[15]);
        ((uint4*)xq)[t] = q;
    } else if (b < CVTBLK + NBE) {
        int bb = b - CVTBLK;
        for (int j = tid; j < NBUCKET; j += 256) lh[j] = 0;
        __syncthreads();
        int flag = *flagp;
        int eb = bb * ECHK;
        #pragma unroll
        for (int k = 0; k < ECHK / 256; ++k) {
            int e = eb + k * 256 + tid;
            if (e < EE) {
                int r, c; load_edge(ei, e, flag, r, c);
                unsigned key = (r == c) ? 0xFFFFu : (unsigned)r;
                float w = ew[e];
                items[e] = ((unsigned long long)((key << 16) | (unsigned)c) << 32)
                           | (unsigned long long)__float_as_uint(w);
                atomicAdd(&lh[min(key >> 7, (unsigned)NBKT_REAL)], 1);  // LDS
            }
        }
        __syncthreads();
        for (int j = tid; j < NBUCKET; j += 256) hist[j * NBE + bb] = lh[j];
    } else {
        int t = (b - CVTBLK - NBE) * 256 + tid;
        if (t >= 3 * FF * 168) return;
        int ph = t / (FF * 168);
        int rem = t - ph * FF * 168;
        int o = rem / 168;
        int i = rem - o * 168;
        short v = 0;
        if (i < FF) {
            bf16 bv = (bf16)wt[ph * FF * FF + i * FF + o];
            v = *(const short*)&bv;
        }
        wtb[t] = v;
    }
}

// ---------------- generic 2-level exclusive scan of hist[HM] (in place) ----------------
// After scanA1+scanA2: base(f) = hist[f] + bsumA[f>>8].

__global__ void scanA1_k(int* __restrict__ hist, int* __restrict__ bsumA) {
    __shared__ int wsum[4], woff[4];
    int b = blockIdx.x, tid = threadIdx.x;
    int wv = tid >> 6, ln = tid & 63;
    int i = b * 256 + tid;
    int v = (i < HM) ? hist[i] : 0;
    int xs = v;
    #pragma unroll
    for (int off = 1; off < 64; off <<= 1) {
        int t = __shfl_up(xs, off, 64);
        if (ln >= off) xs += t;
    }
    if (ln == 63) wsum[wv] = xs;
    __syncthreads();
    if (tid == 0) {
        int s = 0;
        #pragma unroll
        for (int j = 0; j < 4; ++j) { woff[j] = s; s += wsum[j]; }
        bsumA[b] = s;
    }
    __syncthreads();
    if (i < HM) hist[i] = woff[wv] + (xs - v);
}

__global__ __launch_bounds__(1024) void scanA2_k(int* __restrict__ bsumA) {
    __shared__ int wsum[16], woff[16];
    int tid = threadIdx.x, wv = tid >> 6, ln = tid & 63;
    int v = (tid < SCANBLK) ? bsumA[tid] : 0;
    int xs = v;
    #pragma unroll
    for (int off = 1; off < 64; off <<= 1) {
        int t = __shfl_up(xs, off, 64);
        if (ln >= off) xs += t;
    }
    if (ln == 63) wsum[wv] = xs;
    __syncthreads();
    if (tid == 0) {
        int s = 0;
        #pragma unroll
        for (int j = 0; j < 16; ++j) { woff[j] = s; s += wsum[j]; }
    }
    __syncthreads();
    if (tid < SCANBLK) bsumA[tid] = woff[wv] + (xs - v);
}

__device__ inline int hbase(const int* hist, const int* bsumA, int f) {
    return hist[f] + bsumA[f >> 8];
}

// ---------------- partition scatter: items -> sorted (grouped by bucket) ----------------
// lbase doubles as the fill counter (LDS returning atomics only).

__global__ void pscat_k(const unsigned long long* __restrict__ items,
                        const int* __restrict__ hist, const int* __restrict__ bsumA,
                        unsigned long long* __restrict__ sorted) {
    __shared__ int lbase[NBUCKET];
    int b = blockIdx.x, tid = threadIdx.x;
    for (int j = tid; j < NBUCKET; j += 256) {
        int f = j * NBE + b;
        lbase[j] = hbase(hist, bsumA, f);
    }
    __syncthreads();
    int eb = b * ECHK;
    #pragma unroll
    for (int k = 0; k < ECHK / 256; ++k) {
        int e = eb + k * 256 + tid;
        if (e < EE) {
            unsigned long long it = items[e];
            unsigned key = (unsigned)(it >> 48);
            int bk = (int)min(key >> 7, (unsigned)NBKT_REAL);
            int slot = atomicAdd(&lbase[bk], 1);   // LDS
            sorted[slot] = it;
        }
    }
}

// ---------------- fine1: per-bucket row histogram -> rowptr + dinv ----------------
// Bucket b owns rows [b*128, b*128+128); all its edges are contiguous in sorted.

__global__ void fine1_k(const unsigned long long* __restrict__ sorted,
                        const int* __restrict__ hist, const int* __restrict__ bsumA,
                        int* __restrict__ rowptr, float* __restrict__ dinv) {
    __shared__ int lh[128];
    __shared__ int wtot;
    int b = blockIdx.x, tid = threadIdx.x;
    if (tid < 128) lh[tid] = 0;
    int s = hbase(hist, bsumA, b * NBE);
    int e = hbase(hist, bsumA, (b + 1) * NBE);
    __syncthreads();
    for (int p = s + tid; p < e; p += 256)
        atomicAdd(&lh[(int)(unsigned)(sorted[p] >> 48) - b * 128], 1);  // LDS
    __syncthreads();
    int ln = tid & 63;
    int v = (tid < 128) ? lh[tid] : 0;
    int xs = v;
    #pragma unroll
    for (int off = 1; off < 64; off <<= 1) {
        int t = __shfl_up(xs, off, 64);
        if (ln >= off) xs += t;
    }
    if (tid == 63) wtot = xs;
    __syncthreads();
    int excl = xs - v + ((tid >= 64 && tid < 128) ? wtot : 0);
    int gr = b * 128 + tid;
    if (tid < 128 && gr < NN) {
        rowptr[gr] = s + excl;
        dinv[gr] = v > 0 ? rsqrtf((float)v) : 0.f;
    }
    if (b == NBKT_REAL - 1 && tid == 0) rowptr[NN] = e;  // end of real edges
}

// ---------------- fine2: write pairs in CSR order (coalesced region per bucket) ----------------
// lrp doubles as the fill counter (starts at rowptr). packed (col:16 | bf16(lap):16).

__global__ void fine2_k(const unsigned long long* __restrict__ sorted,
                        const int* __restrict__ hist, const int* __restrict__ bsumA,
                        const int* __restrict__ rowptr, const float* __restrict__ dinv,
                        unsigned* __restrict__ pairs) {
    __shared__ int lrp[128];
    __shared__ float ldv[128];
    int b = blockIdx.x, tid = threadIdx.x;
    int gr = b * 128 + tid;
    if (tid < 128) {
        lrp[tid] = (gr < NN) ? rowptr[gr] : 0;
        ldv[tid] = (gr < NN) ? dinv[gr] : 0.f;
    }
    int s = hbase(hist, bsumA, b * NBE);
    int e = hbase(hist, bsumA, (b + 1) * NBE);
    __syncthreads();
    for (int p = s + tid; p < e; p += 256) {
        unsigned long long it = sorted[p];
        int lr = (int)(unsigned)(it >> 48) - b * 128;
        unsigned c = (unsigned)(it >> 32) & 0xFFFFu;
        float w = __uint_as_float((unsigned)it);
        float lap = -ldv[lr] * dinv[c] * w;
        int slot = atomicAdd(&lrp[lr], 1);   // LDS
        bf16 lb = (bf16)lap;
        pairs[slot] = c | ((unsigned)*(unsigned short*)&lb << 16);
    }
}

// ---------------- SpMM fp8-gather: 9 threads/node, 16 fp8/edge, packed 4B edge stream ----------------

template <int MODE>
__global__ void spmm_k(const unsigned char* __restrict__ vq, const bf16* __restrict__ x0,
                       const int* __restrict__ rowptr, const unsigned* __restrict__ pairs,
                       bf16* __restrict__ y, unsigned char* __restrict__ yq) {
    int t = blockIdx.x * 256 + threadIdx.x;
    if (t >= NN * 9) return;
    int i = t / 9;
    int fo = (t - i * 9) * 16;
    const unsigned char* vp = vq + fo;

    float a[16];
    #pragma unroll
    for (int j = 0; j < 16; ++j) a[j] = 0.f;

    int s = rowptr[i], e = rowptr[i + 1];
    int p = s;
    for (; p + 1 < e; p += 2) {
        unsigned pr0 = pairs[p], pr1 = pairs[p + 1];
        uint4 u0 = *(const uint4*)(vp + (pr0 & 0xffffu) * FF);
        uint4 u1 = *(const uint4*)(vp + (pr1 & 0xffffu) * FF);
        fma16q(a, bhi(pr0), u0);
        fma16q(a, bhi(pr1), u1);
    }
    if (p < e) {
        unsigned pr = pairs[p];
        uint4 u = *(const uint4*)(vp + (pr & 0xffffu) * FF);
        fma16q(a, bhi(pr), u);
    }

    if (MODE == 1) {
        const uint4* xp = (const uint4*)((const unsigned short*)x0 + i * FF + fo);
        uint4 u0 = xp[0], u1 = xp[1];
        a[0]  = 2.f * a[0]  - blo(u0.x);  a[1]  = 2.f * a[1]  - bhi(u0.x);
        a[2]  = 2.f * a[2]  - blo(u0.y);  a[3]  = 2.f * a[3]  - bhi(u0.y);
        a[4]  = 2.f * a[4]  - blo(u0.z);  a[5]  = 2.f * a[5]  - bhi(u0.z);
        a[6]  = 2.f * a[6]  - blo(u0.w);  a[7]  = 2.f * a[7]  - bhi(u0.w);
        a[8]  = 2.f * a[8]  - blo(u1.x);  a[9]  = 2.f * a[9]  - bhi(u1.x);
        a[10] = 2.f * a[10] - blo(u1.y);  a[11] = 2.f * a[11] - bhi(u1.y);
        a[12] = 2.f * a[12] - blo(u1.z);  a[13] = 2.f * a[13] - bhi(u1.z);
        a[14] = 2.f * a[14] - blo(u1.w);  a[15] = 2.f * a[15] - bhi(u1.w);
    }

    unsigned short hs[16];
    #pragma unroll
    for (int j = 0; j < 16; ++j) {
        bf16 b = (bf16)a[j];
        hs[j] = *(unsigned short*)&b;
    }
    uint4* yp = (uint4*)((unsigned short*)y + i * FF + fo);
    yp[0] = ((uint4*)hs)[0];
    yp[1] = ((uint4*)hs)[1];

    if (MODE == 0) {
        uint4 q;
        q.x = enc4(a[0], a[1], a[2], a[3]);
        q.y = enc4(a[4], a[5], a[6], a[7]);
        q.z = enc4(a[8], a[9], a[10], a[11]);
        q.w = enc4(a[12], a[13], a[14], a[15]);
        *(uint4*)(yq + i * FF + fo) = q;
    }
}

// ---------------- fused MFMA GEMM: full W resident in LDS, 1 block/CU, 16 waves ----------------

__global__ __launch_bounds__(1024)
void gemm_fused(const bf16* __restrict__ A0, const bf16* __restrict__ A1,
                const bf16* __restrict__ A2, const short* __restrict__ wtb,
                const float* __restrict__ bias, float* __restrict__ out) {
    __shared__ __align__(16) short Wt[3 * 144 * 168];   // 145,152 B
    int tid = threadIdx.x;

    {
        const uint4* Wg = (const uint4*)wtb;
        uint4* Wl = (uint4*)Wt;
        #pragma unroll
        for (int q = 0; q < 9; ++q) {
            int idx = q * 1024 + tid;
            if (idx < 9072) Wl[idx] = Wg[idx];
        }
    }
    __syncthreads();   // the ONLY barrier

    int wv = tid >> 6, ln = tid & 63;
    int m16 = ln & 15, quad = ln >> 4;
    int tile = wv * 256 + blockIdx.x;
    if (tile * 16 >= NN) return;
    int rowBase = tile * 16;
    int row = rowBase + m16;

    const bf16* const srcs[3] = {A0, A1, A2};
    const short8 zero8 = {0, 0, 0, 0, 0, 0, 0, 0};

    floatx4 acc[9];
    #pragma unroll
    for (int q = 0; q < 9; ++q) acc[q] = (floatx4){0.f, 0.f, 0.f, 0.f};

    #pragma unroll
    for (int ph = 0; ph < 3; ++ph) {
        const bf16* A = srcs[ph];
        short8 a[5];
        #pragma unroll
        for (int kt = 0; kt < 5; ++kt) {
            int k0 = kt * 32 + quad * 8;
            if (k0 < FF)
                a[kt] = *(const short8*)((const short*)A + row * FF + k0);
            else
                a[kt] = zero8;
        }

        const short* Wp = Wt + ph * 144 * 168;
        #pragma unroll
        for (int nt = 0; nt < 9; ++nt) {
            #pragma unroll
            for (int kt = 0; kt < 5; ++kt) {
                short8 b = *(const short8*)&Wp[(nt * 16 + m16) * 168 + kt * 32 + quad * 8];
                acc[nt] = __builtin_amdgcn_mfma_f32_16x16x32_bf16(a[kt], b, acc[nt], 0, 0, 0);
            }
        }
    }

    int rowc = rowBase + quad * 4;
    #pragma unroll
    for (int nt = 0; nt < 9; ++nt) {
        int col = nt * 16 + m16;
        float bs = bias[col];
        #pragma unroll
        for (int r = 0; r < 4; ++r) {
            int rr = rowc + r;
            out[rr * FF + col] = acc[nt][r] + bs;
        }
    }
}

// ---------------- launch ----------------

extern "C" void kernel_launch(void* const* d_in, const int* in_sizes, int n_in,
                              void* d_out, int out_size, void* d_ws, size_t ws_size,
                              hipStream_t stream) {
    int ix = -1, iei = -1, iew = -1, iwt = -1, ib = -1;
    for (int i = 0; i < n_in; ++i) {
        switch (in_sizes[i]) {
            case NN * FF:      if (ix  < 0) ix  = i; break;
            case 2 * EE:       if (iei < 0) iei = i; break;
            case EE:           if (iew < 0) iew = i; break;
            case 3 * FF * FF:  if (iwt < 0) iwt = i; break;
            case FF:           if (ib  < 0) ib  = i; break;
        }
    }
    if (ix < 0 || iei < 0 || iew < 0 || iwt < 0 || ib < 0) {
        ix = 0; iei = 1; iew = 2; iwt = 3; ib = 4;
    }
    const float* x    = (const float*)d_in[ix];
    const int*   ei   = (const int*)d_in[iei];
    const float* ew   = (const float*)d_in[iew];
    const float* wt   = (const float*)d_in[iwt];
    const float* bias = (const float*)d_in[ib];
    float* out = (float*)d_out;

    // Workspace layout (75.3 MB, all offsets 16B-aligned):
    char* p = (char*)d_ws;
    unsigned long long* items  = (unsigned long long*)(p + 0);          // 6.4 MB
    unsigned long long* sorted = (unsigned long long*)(p + 6400000);    // 6.4 MB
    int*      hist   = (int*)(p + 12800000);             // HM ints = 613 KB
    int*      bsumA  = (int*)(p + 13500000);             // SCANBLK ints
    int*      rowptr = (int*)(p + 13600000);             // N+1 ints
    float*    dinv   = (float*)(p + 13900000);           // N floats
    unsigned* pairs  = (unsigned*)(p + 14200000);        // E words = 3.2 MB
    int*      eflag  = (int*)(p + 17400000);
    short*    wtb    = (short*)(p + 17500000);           // 145,152 B
    bf16*     tx1    = (bf16*)(p + 17700000);            // 14.4 MB
    bf16*     tx2    = (bf16*)(p + 32100000);            // 14.4 MB
    unsigned char* xq   = (unsigned char*)(p + 46500000); // 7.2 MB
    unsigned char* tx1q = (unsigned char*)(p + 53700000); // 7.2 MB
    bf16*     xb     = (bf16*)(p + 60900000);            // 14.4 MB -> ends 75,300,000

    if (ws_size < 75300000) return;

    int spGrid = (NN * 9 + 255) / 256;

    detect_k<<<1, 256, 0, stream>>>(ei, eflag);
    fusedA_k<<<CVTBLK + NBE + WGRID, 256, 0, stream>>>(x, xb, xq, ei, ew, items, hist,
                                                       wt, wtb, eflag);
    scanA1_k<<<SCANBLK, 256, 0, stream>>>(hist, bsumA);
    scanA2_k<<<1, 1024, 0, stream>>>(bsumA);
    pscat_k<<<NBE, 256, 0, stream>>>(items, hist, bsumA, sorted);
    fine1_k<<<NBKT_REAL, 256, 0, stream>>>(sorted, hist, bsumA, rowptr, dinv);
    fine2_k<<<NBKT_REAL, 256, 0, stream>>>(sorted, hist, bsumA, rowptr, dinv, pairs);

    spmm_k<0><<<spGrid, 256, 0, stream>>>(xq, xb, rowptr, pairs, tx1, tx1q);
    spmm_k<1><<<spGrid, 256, 0, stream>>>(tx1q, xb, rowptr, pairs, tx2, (unsigned char*)0);
    gemm_fused<<<256, 1024, 0, stream>>>(xb, tx1, tx2, wtb, bias, out);
}